// Round 4
// baseline (242.729 us; speedup 1.0000x reference)
//
#include <hip/hip_runtime.h>
#include <hip/hip_bf16.h>

// Loss = L1*sl1(1,iou) + L2*sl1(t[:4],p[:4]) + L3*sl1(t[12],p[12]) + 0.5*L4*sl1(t[4:12],p[4:12])
// shapes: (B=256, N=8192, F=13) fp32. B*N = 2^21 rows.
//
// Key decomposition: loss2/3/4 are elementwise over the flat arrays with a
// weight depending only on (flat_index mod 13). Only the IoU term needs the
// 4 box features of a row together. So:
//   Part A: flat float4 streaming pass (fully coalesced, no LDS, no barriers),
//           per-element weight by mod-13.
//   Part B: per-row IoU from 8 scalar dword loads of f0..3 — same addresses
//           Part A just touched in this block => L2-hot, ~no HBM cost.
// 2048 blocks x 256 thr (8 blocks/CU), one 1024-row chunk per block.
// Partials to d_ws; stage2 sums 2048 partials. No atomics, no memset.

#define ROWS_TOTAL   (256 * 8192)          // 2^21
#define ROWS_PER_BLK 1024
#define NBLK         (ROWS_TOTAL / ROWS_PER_BLK)   // 2048
#define F4_PER_BLK   (ROWS_PER_BLK * 13 / 4)       // 3328 float4 per tensor per block

// Exact power-of-two mean weights (B*N = 2^21):
#define W1 (1.0f / 2097152.0f)    // loss1: 1/(B*N)
#define W2 (1.0f / 8388608.0f)    // loss2: 1/(B*N*4)
#define W3 (1.0f / 2097152.0f)    // loss3: 1/(B*N)
#define W4 (1.0f / 33554432.0f)   // loss4: 0.5/(B*N*8)

__device__ __forceinline__ float sl1(float d) {
    d = fabsf(d);
    return d < 1.0f ? 0.5f * d * d : d - 0.5f;
}

__global__ __launch_bounds__(256) void loss_stage1(const float* __restrict__ T,
                                                   const float* __restrict__ P,
                                                   float* __restrict__ partial) {
    __shared__ float wred[4];
    const int tid = threadIdx.x;
    const int blk = blockIdx.x;

    float acc = 0.0f;

    // ---- Part A: flat elementwise pass, float4, per-element mod-13 weight ----
    {
        const float4* t4 = (const float4*)T + (long long)blk * F4_PER_BLK;
        const float4* p4 = (const float4*)P + (long long)blk * F4_PER_BLK;
        const unsigned ebase = (unsigned)blk * (F4_PER_BLK * 4u);
#pragma unroll
        for (int k = 0; k < 13; ++k) {
            const int i = k * 256 + tid;
            float4 a = t4[i];
            float4 b = p4[i];
            unsigned f0 = (ebase + 4u * (unsigned)i) % 13u;   // magic-mul, no div
            const float da[4] = {a.x - b.x, a.y - b.y, a.z - b.z, a.w - b.w};
#pragma unroll
            for (int j = 0; j < 4; ++j) {
                unsigned f = f0 + (unsigned)j;
                if (f >= 13u) f -= 13u;
                float w = (f < 4u) ? W2 : ((f == 12u) ? W3 : W4);
                acc += w * sl1(da[j]);
            }
        }
    }

    // ---- Part B: IoU over this block's 1024 rows (L2-hot re-read of f0..3) ----
    {
#pragma unroll
        for (int k = 0; k < 4; ++k) {
            const long long r = (long long)blk * ROWS_PER_BLK + k * 256 + tid;
            const float* tr = T + r * 13;
            const float* pr = P + r * 13;
            float t0 = tr[0], t1 = tr[1], t2 = tr[2], t3 = tr[3];
            float p0 = pr[0], p1 = pr[1], p2 = pr[2], p3 = pr[3];

            float w = fmaxf(fminf(t2, p2) - fmaxf(t0, p0), 0.0f);
            float h = fmaxf(fminf(t3, p3) - fmaxf(t1, p1), 0.0f);
            float inter = w * h;
            float a1 = (t2 - t0) * (t3 - t1);
            float a2 = (p2 - p0) * (p3 - p1);
            float u  = a1 + a2 - inter + 1e-7f;
            float iou = inter * __builtin_amdgcn_rcpf(u);
            acc += W1 * sl1(1.0f - iou);
        }
    }

    // ---- Block reduction: wave64 shuffle -> 4-wave LDS -> one partial ----
#pragma unroll
    for (int off = 32; off > 0; off >>= 1)
        acc += __shfl_down(acc, off, 64);
    if ((tid & 63) == 0) wred[tid >> 6] = acc;
    __syncthreads();
    if (tid == 0)
        partial[blk] = wred[0] + wred[1] + wred[2] + wred[3];
}

__global__ __launch_bounds__(256) void loss_stage2(const float* __restrict__ partial,
                                                   float* __restrict__ out) {
    __shared__ float wred[4];
    const int tid = threadIdx.x;
    float a = 0.0f;
#pragma unroll
    for (int k = 0; k < NBLK / 256; ++k) a += partial[k * 256 + tid];
#pragma unroll
    for (int off = 32; off > 0; off >>= 1)
        a += __shfl_down(a, off, 64);
    if ((tid & 63) == 0) wred[tid >> 6] = a;
    __syncthreads();
    if (tid == 0) out[0] = wred[0] + wred[1] + wred[2] + wred[3];
}

extern "C" void kernel_launch(void* const* d_in, const int* in_sizes, int n_in,
                              void* d_out, int out_size, void* d_ws, size_t ws_size,
                              hipStream_t stream) {
    const float* targets = (const float*)d_in[0];
    const float* preds   = (const float*)d_in[1];
    float* out     = (float*)d_out;
    float* partial = (float*)d_ws;   // NBLK floats = 8 KB scratch

    loss_stage1<<<NBLK, 256, 0, stream>>>(targets, preds, partial);
    loss_stage2<<<1, 256, 0, stream>>>(partial, out);
}